// Round 1
// baseline (149.191 us; speedup 1.0000x reference)
//
#include <hip/hip_runtime.h>
#include <math.h>

#define N_FRAMES 20000
#define N_BEADS  50
#define N_DIST   1225   // sum_{inc=1}^{49} (50-inc)
#define N_ANG    48
#define N_DIH    47
#define OUT_STRIDE (N_DIST + N_ANG + 2 * N_DIH)  // 1367

// cumulative pair count before separation `inc`:
// cum(inc) = sum_{k=1}^{inc-1} (50-k) = (inc-1)*50 - (inc-1)*inc/2
__device__ __forceinline__ int cum_pairs(int inc) {
    return (inc - 1) * 50 - ((inc - 1) * inc) / 2;
}

__global__ __launch_bounds__(256)
void protein_feat_kernel(const float* __restrict__ data, float* __restrict__ out) {
    const int f   = blockIdx.x;
    const int tid = threadIdx.x;

    __shared__ float s[N_BEADS * 3];  // frame coords, AoS [bead][xyz]

    const float* fd = data + (size_t)f * (N_BEADS * 3);
    if (tid < N_BEADS * 3) s[tid] = fd[tid];
    __syncthreads();

    float* fout = out + (size_t)f * OUT_STRIDE;

    // ---- distances: pairs ordered by separation inc, then start index i ----
    for (int p = tid; p < N_DIST; p += 256) {
        // invert cum(inc) <= p < cum(inc+1): inc = floor((101 - sqrt(9801 - 8p))/2)
        float disc = 9801.0f - 8.0f * (float)p;
        int inc = (int)((101.0f - sqrtf(disc)) * 0.5f);
        inc = min(max(inc, 1), 49);
        while (inc < 49 && cum_pairs(inc + 1) <= p) ++inc;   // float-rounding fixup
        while (inc > 1  && cum_pairs(inc)     >  p) --inc;
        int i = p - cum_pairs(inc);
        int j = i + inc;

        float dx = s[3 * j + 0] - s[3 * i + 0];
        float dy = s[3 * j + 1] - s[3 * i + 1];
        float dz = s[3 * j + 2] - s[3 * i + 2];
        fout[p] = sqrtf(dx * dx + dy * dy + dz * dz);
    }

    // ---- angles (wave 0): beads (a, a+1, a+2), angle at middle bead ----
    if (tid < N_ANG) {
        int a = tid;
        float b1x = s[3 * a + 0] - s[3 * (a + 1) + 0];
        float b1y = s[3 * a + 1] - s[3 * (a + 1) + 1];
        float b1z = s[3 * a + 2] - s[3 * (a + 1) + 2];
        float b2x = s[3 * (a + 2) + 0] - s[3 * (a + 1) + 0];
        float b2y = s[3 * (a + 2) + 1] - s[3 * (a + 1) + 1];
        float b2z = s[3 * (a + 2) + 2] - s[3 * (a + 1) + 2];
        float dot = b1x * b2x + b1y * b2y + b1z * b2z;
        float n1 = sqrtf(b1x * b1x + b1y * b1y + b1z * b1z);
        float n2 = sqrtf(b2x * b2x + b2y * b2y + b2z * b2z);
        float c = dot / (n1 * n2);
        c = fminf(1.0f, fmaxf(-1.0f, c));
        fout[N_DIST + a] = acosf(c);
    }

    // ---- dihedrals (wave 1): beads (d, d+1, d+2, d+3) ----
    if (tid >= 64 && tid < 64 + N_DIH) {
        int d = tid - 64;
        float ax = s[3 * (d + 1) + 0] - s[3 * d + 0];
        float ay = s[3 * (d + 1) + 1] - s[3 * d + 1];
        float az = s[3 * (d + 1) + 2] - s[3 * d + 2];
        float bx = s[3 * (d + 2) + 0] - s[3 * (d + 1) + 0];
        float by = s[3 * (d + 2) + 1] - s[3 * (d + 1) + 1];
        float bz = s[3 * (d + 2) + 2] - s[3 * (d + 1) + 2];
        float cx = s[3 * (d + 3) + 0] - s[3 * (d + 2) + 0];
        float cy = s[3 * (d + 3) + 1] - s[3 * (d + 2) + 1];
        float cz = s[3 * (d + 3) + 2] - s[3 * (d + 2) + 2];

        // p1 = a x b ; p2 = b x c
        float p1x = ay * bz - az * by;
        float p1y = az * bx - ax * bz;
        float p1z = ax * by - ay * bx;
        float p2x = by * cz - bz * cy;
        float p2y = bz * cx - bx * cz;
        float p2z = bx * cy - by * cx;

        float n1 = sqrtf(p1x * p1x + p1y * p1y + p1z * p1z);
        float n2 = sqrtf(p2x * p2x + p2y * p2y + p2z * p2z);
        float nb = sqrtf(bx * bx + by * by + bz * bz);

        float dotp = p1x * p2x + p1y * p2y + p1z * p2z;
        // (p1 x p2) . b
        float qx = p1y * p2z - p1z * p2y;
        float qy = p1z * p2x - p1x * p2z;
        float qz = p1x * p2y - p1y * p2x;
        float trip = qx * bx + qy * by + qz * bz;

        float inv12 = 1.0f / (n1 * n2);
        fout[N_DIST + N_ANG + d]          = dotp * inv12;
        fout[N_DIST + N_ANG + N_DIH + d]  = trip * inv12 / nb;
    }
}

extern "C" void kernel_launch(void* const* d_in, const int* in_sizes, int n_in,
                              void* d_out, int out_size, void* d_ws, size_t ws_size,
                              hipStream_t stream) {
    const float* data = (const float*)d_in[0];
    float* out = (float*)d_out;
    protein_feat_kernel<<<N_FRAMES, 256, 0, stream>>>(data, out);
}

// Round 2
// 131.115 us; speedup vs baseline: 1.1379x; 1.1379x over previous
//
#include <hip/hip_runtime.h>
#include <math.h>

#define N_FRAMES 20000
#define N_BEADS  50
#define N_DIST   1225   // sum_{inc=1}^{49} (50-inc)
#define N_ANG    48
#define N_DIH    47
#define OUT_STRIDE (N_DIST + N_ANG + 2 * N_DIH)  // 1367
#define FPB      8      // frames per block; 20000/8 = 2500 blocks
#define FRAME_F  (N_BEADS * 3)   // 150 floats per frame

// cumulative pair count before separation `inc`:
// cum(inc) = sum_{k=1}^{inc-1} (50-k) = (inc-1)*50 - (inc-1)*inc/2
__device__ __forceinline__ int cum_pairs(int inc) {
    return (inc - 1) * 50 - ((inc - 1) * inc) / 2;
}

__global__ __launch_bounds__(256)
void protein_feat_kernel(const float* __restrict__ data, float* __restrict__ out) {
    const int tid = threadIdx.x;
    const int f0  = blockIdx.x * FPB;

    __shared__ __align__(16) float s[FPB * FRAME_F];  // 8 frames x 150 floats = 4.8 KB

    // ---- stage 8 frames with float4 loads (1200 floats = 300 float4) ----
    {
        const float4* g4 = (const float4*)(data + (size_t)f0 * FRAME_F);
        float4* s4 = (float4*)s;
        for (int x = tid; x < FPB * FRAME_F / 4; x += 256) s4[x] = g4[x];
    }
    __syncthreads();

    // ---- precompute this thread's pair indices ONCE (reused for all 8 frames) ----
    // pairs ordered by separation inc (1..49), then start index i
    int i3[5], j3[5];
#pragma unroll
    for (int k = 0; k < 5; ++k) {
        int p = tid + k * 256;
        if (p < N_DIST) {
            float disc = 9801.0f - 8.0f * (float)p;
            int inc = (int)((101.0f - sqrtf(disc)) * 0.5f);
            inc = min(max(inc, 1), 49);
            while (inc < 49 && cum_pairs(inc + 1) <= p) ++inc;  // float-rounding fixup
            while (inc > 1  && cum_pairs(inc)     >  p) --inc;
            int i = p - cum_pairs(inc);
            i3[k] = 3 * i;
            j3[k] = 3 * (i + inc);
        } else {
            i3[k] = 0; j3[k] = 0;
        }
    }

    // ---- distances: 8 frames x 1225 pairs ----
#pragma unroll
    for (int f = 0; f < FPB; ++f) {
        const float* sf = s + f * FRAME_F;
        float* fout = out + (size_t)(f0 + f) * OUT_STRIDE;
#pragma unroll
        for (int k = 0; k < 5; ++k) {
            int p = tid + k * 256;
            if (p < N_DIST) {
                float dx = sf[j3[k] + 0] - sf[i3[k] + 0];
                float dy = sf[j3[k] + 1] - sf[i3[k] + 1];
                float dz = sf[j3[k] + 2] - sf[i3[k] + 2];
                fout[p] = sqrtf(dx * dx + dy * dy + dz * dz);
            }
        }
    }

    // ---- angles: 8 frames x 48 = 384 items ----
    for (int idx = tid; idx < FPB * N_ANG; idx += 256) {
        int f = idx / N_ANG;
        int a = idx - f * N_ANG;
        const float* sf = s + f * FRAME_F;
        float b1x = sf[3 * a + 0] - sf[3 * (a + 1) + 0];
        float b1y = sf[3 * a + 1] - sf[3 * (a + 1) + 1];
        float b1z = sf[3 * a + 2] - sf[3 * (a + 1) + 2];
        float b2x = sf[3 * (a + 2) + 0] - sf[3 * (a + 1) + 0];
        float b2y = sf[3 * (a + 2) + 1] - sf[3 * (a + 1) + 1];
        float b2z = sf[3 * (a + 2) + 2] - sf[3 * (a + 1) + 2];
        float dot = b1x * b2x + b1y * b2y + b1z * b2z;
        float n1 = sqrtf(b1x * b1x + b1y * b1y + b1z * b1z);
        float n2 = sqrtf(b2x * b2x + b2y * b2y + b2z * b2z);
        float c = dot / (n1 * n2);
        c = fminf(1.0f, fmaxf(-1.0f, c));
        out[(size_t)(f0 + f) * OUT_STRIDE + N_DIST + a] = acosf(c);
    }

    // ---- dihedrals: 8 frames x 47 = 376 items ----
    for (int idx = tid; idx < FPB * N_DIH; idx += 256) {
        int f = idx / N_DIH;
        int d = idx - f * N_DIH;
        const float* sf = s + f * FRAME_F;
        float ax = sf[3 * (d + 1) + 0] - sf[3 * d + 0];
        float ay = sf[3 * (d + 1) + 1] - sf[3 * d + 1];
        float az = sf[3 * (d + 1) + 2] - sf[3 * d + 2];
        float bx = sf[3 * (d + 2) + 0] - sf[3 * (d + 1) + 0];
        float by = sf[3 * (d + 2) + 1] - sf[3 * (d + 1) + 1];
        float bz = sf[3 * (d + 2) + 2] - sf[3 * (d + 1) + 2];
        float cx = sf[3 * (d + 3) + 0] - sf[3 * (d + 2) + 0];
        float cy = sf[3 * (d + 3) + 1] - sf[3 * (d + 2) + 1];
        float cz = sf[3 * (d + 3) + 2] - sf[3 * (d + 2) + 2];

        // p1 = a x b ; p2 = b x c
        float p1x = ay * bz - az * by;
        float p1y = az * bx - ax * bz;
        float p1z = ax * by - ay * bx;
        float p2x = by * cz - bz * cy;
        float p2y = bz * cx - bx * cz;
        float p2z = bx * cy - by * cx;

        float n1 = sqrtf(p1x * p1x + p1y * p1y + p1z * p1z);
        float n2 = sqrtf(p2x * p2x + p2y * p2y + p2z * p2z);
        float nb = sqrtf(bx * bx + by * by + bz * bz);

        float dotp = p1x * p2x + p1y * p2y + p1z * p2z;
        // (p1 x p2) . b
        float qx = p1y * p2z - p1z * p2y;
        float qy = p1z * p2x - p1x * p2z;
        float qz = p1x * p2y - p1y * p2x;
        float trip = qx * bx + qy * by + qz * bz;

        float inv12 = 1.0f / (n1 * n2);
        size_t base = (size_t)(f0 + f) * OUT_STRIDE + N_DIST + N_ANG;
        out[base + d]         = dotp * inv12;
        out[base + N_DIH + d] = trip * inv12 / nb;
    }
}

extern "C" void kernel_launch(void* const* d_in, const int* in_sizes, int n_in,
                              void* d_out, int out_size, void* d_ws, size_t ws_size,
                              hipStream_t stream) {
    const float* data = (const float*)d_in[0];
    float* out = (float*)d_out;
    protein_feat_kernel<<<N_FRAMES / FPB, 256, 0, stream>>>(data, out);
}